// Round 5
// baseline (29474.448 us; speedup 1.0000x reference)
//
#include <hip/hip_runtime.h>
#include <hip/hip_bf16.h>
#include <math.h>

// Problem dims
#define B_  128
#define T_  512
#define I_  256
#define H_  512
#define O_  256
#define NP  2048            // 4*H (gate-interleaved n' = h*4+g)
#define BT  65536           // B*T
#define HB  65536           // H*B  (hist row: [128 b][512 h])

// Scan decomposition: 16 batch-groups (8 b) x 16 n'-blocks (128 n') = 256 blocks.
// Groups fully independent => sync is 16-wide, group-local.
// WORKSPACE BUDGET: <= ~210 MB (R2-proven). xp precompute (512 MB) is OUT;
// x-projection folds into the scan, computed before the sync wait.

// ---------------------------------------------------------------------------
// Prep: transposed weight layouts + fused bias vectors.
//  Wt  [K=512][NP] : Wt[k][h*4+g]  = Wh_g[h][k]
//  WgT [I=256][NP] : WgT[i][h*4+g] = Wx_g[h][i]
//  WphT[H][O]      : WphT[h][o]    = Wph[o][h]
//  cb  [NP]        : Wx_b + b + Wh_b   (all three biases fused)
//  pb  [O]         : Wph_b[o] + bp[o]
// ---------------------------------------------------------------------------
struct PrepArgs {
    const float* Whw[4];
    const float* Wxw[4];
    const float* Wxb[4];
    const float* Whb[4];
    const float* bg[4];
    const float* Wph_w;
    const float* Wph_b;
    const float* bp;
    float* Wt; float* WgT; float* WphT;
    float* cb; float* pb;
};

#define PREP_TOTAL (1048576 + 524288 + 131072 + 2048 + 256)

__global__ __launch_bounds__(256) void k_prep(PrepArgs a) {
    int idx = blockIdx.x * 256 + threadIdx.x;
    if (idx >= PREP_TOTAL) return;
    int q = idx;
    if (q < 1048576) {                       // Wt [512][2048]
        int k = q >> 11, n = q & 2047;
        int g = n & 3, h = n >> 2;
        a.Wt[q] = a.Whw[g][h * H_ + k];
        return;
    }
    q -= 1048576;
    if (q < 524288) {                        // WgT [256][2048]
        int i = q >> 11, n = q & 2047;
        int g = n & 3, h = n >> 2;
        a.WgT[q] = a.Wxw[g][h * I_ + i];
        return;
    }
    q -= 524288;
    if (q < 131072) {                        // WphT [512][256]
        int h = q >> 8, o = q & 255;
        a.WphT[q] = a.Wph_w[o * H_ + h];
        return;
    }
    q -= 131072;
    if (q < 2048) {                          // cb = Wxb + b + Whb
        int g = q & 3, h = q >> 2;
        a.cb[q] = a.Wxb[g][h] + a.bg[g][h] + a.Whb[g][h];
        return;
    }
    q -= 2048;
    a.pb[q] = a.Wph_b[q] + a.bp[q];          // pb
}

// ---------------------------------------------------------------------------
// Transpose x into per-step slices: xT3[t][i][b] = x[b][t][i]
// Grid (4 b-tiles, 8 i-tiles, 512 t), block 256 (32x8).
// ---------------------------------------------------------------------------
__global__ __launch_bounds__(256) void k_xT3(const float* __restrict__ x,
                                             float* __restrict__ xT3) {
    __shared__ float lds[32][33];
    int tid = threadIdx.x;
    int tx = tid & 31, ty = tid >> 5;       // 32 x 8
    int b0 = blockIdx.x * 32;
    int i0 = blockIdx.y * 32;
    int t  = blockIdx.z;
#pragma unroll
    for (int rr = 0; rr < 4; ++rr) {
        int bb = ty + rr * 8;
        lds[bb][tx] = x[((size_t)(b0 + bb) * T_ + t) * I_ + i0 + tx];  // [b][i]
    }
    __syncthreads();
#pragma unroll
    for (int rr = 0; rr < 4; ++rr) {
        int ii = ty + rr * 8;
        xT3[((size_t)t * I_ + i0 + ii) * B_ + b0 + tx] = lds[tx][ii];
    }
}

// ---------------------------------------------------------------------------
// Persistent scan, group-local R2-proven sync, x-projection folded in.
// hist layout: [t][b][k]. Block (grp 0..15, jb 0..15): n' in [jb*128,+128),
// b in [grp*8,+8). 512 threads = 8 waves; wave w: recurrent k-chunk [w*64,+64),
// x i-chunk [w*32,+32). Lane owns 2 n' columns (n0+lane, n0+64+lane).
// Weights persistent in VGPRs: Wt 128 regs + WgT 64 regs.
// Per step: (a) stage x_t -> LDS, (b) x-FMAs (hides sync), (c) poll flag,
// (d) stage h_t, (e) recurrent FMAs, (f) red write, (g) epilogue, (h) publish.
// ---------------------------------------------------------------------------
__device__ inline float sigm(float v) { return 1.f / (1.f + expf(-v)); }

__global__ __launch_bounds__(512, 2) void k_scanp(const float* __restrict__ Wt,   // [512][NP]
                                                  const float* __restrict__ WgT,  // [256][NP]
                                                  const float* __restrict__ xT3,  // [512][256][128]
                                                  const float* __restrict__ cb,   // [NP]
                                                  float* __restrict__ hist,       // [513][128][512]
                                                  int* __restrict__ bar) {        // [512*16]
    __shared__ float x_lds[8 * 260];         // [b][i], stride 260
    __shared__ float h_lds[8 * 516];         // [b][k], stride 516
    __shared__ float red[8 * 128 * 12];      // [wave][col][b], stride 12 (16B-aligned rows)

    int tid = threadIdx.x;
    int wave = tid >> 6, lane = tid & 63;
    int jb  = blockIdx.x & 15;               // n'-block within group
    int grp = blockIdx.x >> 4;               // batch group
    int n0  = jb * 128;
    int kc  = wave * 64;                     // recurrent k-chunk
    int ic  = wave * 32;                     // x i-chunk
    int bg0 = grp * 8;

    // ---- persistent weights in VGPRs ----
    float w0[64], w1[64];
#pragma unroll
    for (int k = 0; k < 64; ++k) {
        w0[k] = Wt[(size_t)(kc + k) * NP + n0 + lane];
        w1[k] = Wt[(size_t)(kc + k) * NP + n0 + 64 + lane];
    }
    float xw0[32], xw1[32];
#pragma unroll
    for (int i = 0; i < 32; ++i) {
        xw0[i] = WgT[(size_t)(ic + i) * NP + n0 + lane];
        xw1[i] = WgT[(size_t)(ic + i) * NP + n0 + 64 + lane];
    }

    // ---- epilogue-thread state (tid < 256 owns one (h,b) cell) ----
    int h_i = tid >> 3, b_l = tid & 7;       // h_i 0..31, b_l 0..7
    float cbv[4] = {0, 0, 0, 0};
    float c_reg = 0.f;
    if (tid < 256) {
#pragma unroll
        for (int g = 0; g < 4; ++g) cbv[g] = cb[n0 + h_i * 4 + g];
    }

    for (int t = 0; t < T_; ++t) {
        // ---- (a) stage x_t slice [256 i][8 b] -> x_lds[b][i] ----
        {
            int i = tid >> 1, q = (tid & 1) * 4;
            float4 xv = *(const float4*)&xT3[((size_t)t * I_ + i) * B_ + bg0 + q];
            x_lds[(q + 0) * 260 + i] = xv.x;
            x_lds[(q + 1) * 260 + i] = xv.y;
            x_lds[(q + 2) * 260 + i] = xv.z;
            x_lds[(q + 3) * 260 + i] = xv.w;
        }
        __syncthreads();

        // ---- (b) x-projection FMAs (no dependence on h -> hides the wait) ----
        float acc0[8], acc1[8];
#pragma unroll
        for (int b = 0; b < 8; ++b) { acc0[b] = 0.f; acc1[b] = 0.f; }
#pragma unroll
        for (int i4 = 0; i4 < 8; ++i4) {
#pragma unroll
            for (int b = 0; b < 8; ++b) {
                float4 xv = *(const float4*)&x_lds[b * 260 + ic + i4 * 4];
                acc0[b] = fmaf(xw0[i4 * 4 + 0], xv.x, acc0[b]);
                acc0[b] = fmaf(xw0[i4 * 4 + 1], xv.y, acc0[b]);
                acc0[b] = fmaf(xw0[i4 * 4 + 2], xv.z, acc0[b]);
                acc0[b] = fmaf(xw0[i4 * 4 + 3], xv.w, acc0[b]);
                acc1[b] = fmaf(xw1[i4 * 4 + 0], xv.x, acc1[b]);
                acc1[b] = fmaf(xw1[i4 * 4 + 1], xv.y, acc1[b]);
                acc1[b] = fmaf(xw1[i4 * 4 + 2], xv.z, acc1[b]);
                acc1[b] = fmaf(xw1[i4 * 4 + 3], xv.w, acc1[b]);
            }
        }

        // ---- (c) wait: all 16 blocks of this group finished step t-1 ----
        if (t > 0 && tid == 0) {
            const int* c = bar + (t - 1) * 16 + grp;
            int spins = 0;
            while (__hip_atomic_load(c, __ATOMIC_RELAXED,
                                     __HIP_MEMORY_SCOPE_AGENT) < 16) {
                __builtin_amdgcn_s_sleep(1);
                if (++spins > 10000000) break;   // loud-wrong beats hang
            }
        }
        __syncthreads();
        __builtin_amdgcn_fence(__ATOMIC_ACQUIRE, "agent");

        // ---- (d) stage h_t slice [8 b][512 k]: wave w stages row b=w ----
        {
            int k8 = lane * 8;
            const float* src = hist + (size_t)t * HB + (size_t)(bg0 + wave) * 512 + k8;
            float* dst = h_lds + wave * 516 + k8;
            *(float4*)(dst + 0) = *(const float4*)(src + 0);
            *(float4*)(dst + 4) = *(const float4*)(src + 4);
        }
        __syncthreads();

        // ---- (e) recurrent FMAs: this wave's 64 k, 8 b, 2 cols ----
#pragma unroll
        for (int k4 = 0; k4 < 16; ++k4) {
#pragma unroll
            for (int b = 0; b < 8; ++b) {
                float4 hv = *(const float4*)&h_lds[b * 516 + kc + k4 * 4];
                acc0[b] = fmaf(w0[k4 * 4 + 0], hv.x, acc0[b]);
                acc0[b] = fmaf(w0[k4 * 4 + 1], hv.y, acc0[b]);
                acc0[b] = fmaf(w0[k4 * 4 + 2], hv.z, acc0[b]);
                acc0[b] = fmaf(w0[k4 * 4 + 3], hv.w, acc0[b]);
                acc1[b] = fmaf(w1[k4 * 4 + 0], hv.x, acc1[b]);
                acc1[b] = fmaf(w1[k4 * 4 + 1], hv.y, acc1[b]);
                acc1[b] = fmaf(w1[k4 * 4 + 2], hv.z, acc1[b]);
                acc1[b] = fmaf(w1[k4 * 4 + 3], hv.w, acc1[b]);
            }
        }

        // ---- (f) write partials ----
        {
            float* r0 = &red[(wave * 128 + lane) * 12];
            float* r1 = &red[(wave * 128 + 64 + lane) * 12];
            *(float4*)(r0 + 0) = *(float4*)&acc0[0];
            *(float4*)(r0 + 4) = *(float4*)&acc0[4];
            *(float4*)(r1 + 0) = *(float4*)&acc1[0];
            *(float4*)(r1 + 4) = *(float4*)&acc1[4];
        }
        __syncthreads();

        // ---- (g) epilogue: reduce 8 partials, gates, cell update, h store ----
        if (tid < 256) {
            float pre[4];
#pragma unroll
            for (int g = 0; g < 4; ++g) {
                int col = h_i * 4 + g;
                float s = 0.f;
#pragma unroll
                for (int w = 0; w < 8; ++w) s += red[(w * 128 + col) * 12 + b_l];
                pre[g] = s + cbv[g];
            }
            float iv = sigm(pre[0]);
            float fv = sigm(pre[1]);
            float gv = tanhf(pre[2]);
            float ov = sigm(pre[3]);
            c_reg = gv * iv + c_reg * fv;
            hist[(size_t)(t + 1) * HB + (size_t)(bg0 + b_l) * 512 + (jb * 32 + h_i)] =
                tanhf(c_reg) * ov;           // plain store (published by RMW-release)
        }
        __syncthreads();                     // h stores + red reads complete
        if (tid == 0)
            __hip_atomic_fetch_add(bar + t * 16 + grp, 1, __ATOMIC_RELEASE,
                                   __HIP_MEMORY_SCOPE_AGENT);
    }
}

// ---------------------------------------------------------------------------
// Output projection per t: out[b][t][o] = hist[t+1][b][:] x WphT + pb (logits).
// Grid (2 o-halves, 512 t), 256 threads, 8x8 micro. Softmax normalizes after.
// ---------------------------------------------------------------------------
__global__ __launch_bounds__(256, 1) void k_outproj(const float* __restrict__ hist, // [513][128][512]
                                                    const float* __restrict__ WphT, // [512][256]
                                                    const float* __restrict__ pb,   // [256]
                                                    float* __restrict__ out) {      // [128][512][256]
    __shared__ float As[16][128];            // [k][b]
    __shared__ float Bs[16][128];            // [k][o]
    int tid = threadIdx.x;
    int tx = tid & 15, ty = tid >> 4;
    int t = blockIdx.y;
    int o0 = blockIdx.x * 128;
    const float* A = hist + (size_t)(t + 1) * HB;   // [128 b][512 k]
    float acc[8][8];
#pragma unroll
    for (int i = 0; i < 8; ++i)
#pragma unroll
        for (int jj = 0; jj < 8; ++jj) acc[i][jj] = 0.f;

    for (int kt = 0; kt < H_; kt += 16) {
#pragma unroll
        for (int pp = 0; pp < 2; ++pp) {
            int p = tid + pp * 256;
            int row = p >> 2, kq = (p & 3) << 2;
            float4 av = *(const float4*)&A[(size_t)row * H_ + kt + kq];
            As[kq + 0][row] = av.x; As[kq + 1][row] = av.y;
            As[kq + 2][row] = av.z; As[kq + 3][row] = av.w;
        }
        {
            int krow = tid >> 5, c4 = (tid & 31) << 2;
            *(float4*)&Bs[krow][c4] =
                *(const float4*)&WphT[(size_t)(kt + krow) * O_ + o0 + c4];
            int krow2 = krow + 8;
            *(float4*)&Bs[krow2][c4] =
                *(const float4*)&WphT[(size_t)(kt + krow2) * O_ + o0 + c4];
        }
        __syncthreads();
#pragma unroll
        for (int k = 0; k < 16; ++k) {
            float a[8], b[8];
            *(float4*)&a[0] = *(const float4*)&As[k][ty * 4];
            *(float4*)&a[4] = *(const float4*)&As[k][64 + ty * 4];
            *(float4*)&b[0] = *(const float4*)&Bs[k][tx * 4];
            *(float4*)&b[4] = *(const float4*)&Bs[k][64 + tx * 4];
#pragma unroll
            for (int i = 0; i < 8; ++i)
#pragma unroll
                for (int jj = 0; jj < 8; ++jj) acc[i][jj] += a[i] * b[jj];
        }
        __syncthreads();
    }
    float4 bv0 = *(const float4*)&pb[o0 + tx * 4];
    float4 bv1 = *(const float4*)&pb[o0 + 64 + tx * 4];
#pragma unroll
    for (int i = 0; i < 8; ++i) {
        int mrow = (i < 4) ? (ty * 4 + i) : (64 + ty * 4 + (i - 4));  // = b index
        float4 v0 = {acc[i][0] + bv0.x, acc[i][1] + bv0.y,
                     acc[i][2] + bv0.z, acc[i][3] + bv0.w};
        float4 v1 = {acc[i][4] + bv1.x, acc[i][5] + bv1.y,
                     acc[i][6] + bv1.z, acc[i][7] + bv1.w};
        float* dst = out + ((size_t)mrow * T_ + t) * O_ + o0;
        *(float4*)(dst + tx * 4) = v0;
        *(float4*)(dst + 64 + tx * 4) = v1;
    }
}

// ---------------------------------------------------------------------------
// In-place softmax over O for each (b,t) row of d_out.
// Grid 2048 = 512 t x 4 b-quarters(32). Block 256 = 32 rows x 8 chunks.
// ---------------------------------------------------------------------------
__global__ __launch_bounds__(256, 1) void k_softmax(float* __restrict__ out) {
    __shared__ float sm[32][260];
    __shared__ float rmax[32][8];
    __shared__ float rsum[32][8];
    int tid = threadIdx.x;
    int t = blockIdx.x >> 2, bq = blockIdx.x & 3;
    int b0 = bq * 32;
    int r = tid >> 3, oc = tid & 7;
    float* base = out + ((size_t)(b0 + r) * T_ + t) * O_ + oc * 32;

#pragma unroll
    for (int q = 0; q < 8; ++q)
        *(float4*)&sm[r][oc * 32 + q * 4] = *(const float4*)(base + q * 4);
    __syncthreads();

    float m = -3.4e38f;
#pragma unroll
    for (int oo = 0; oo < 32; ++oo) m = fmaxf(m, sm[r][oc * 32 + oo]);
    rmax[r][oc] = m;
    __syncthreads();
    float mm = rmax[r][0];
#pragma unroll
    for (int c = 1; c < 8; ++c) mm = fmaxf(mm, rmax[r][c]);

    float s = 0.f;
#pragma unroll
    for (int oo = 0; oo < 32; ++oo) s += expf(sm[r][oc * 32 + oo] - mm);
    rsum[r][oc] = s;
    __syncthreads();
    float st = 0.f;
#pragma unroll
    for (int c = 0; c < 8; ++c) st += rsum[r][c];
    float inv = 1.f / st;

#pragma unroll
    for (int oo = 0; oo < 32; ++oo)
        base[oo] = expf(sm[r][oc * 32 + oo] - mm) * inv;
}

// ---------------------------------------------------------------------------
extern "C" void kernel_launch(void* const* d_in, const int* in_sizes, int n_in,
                              void* d_out, int out_size, void* d_ws, size_t ws_size,
                              hipStream_t stream) {
    const float* x = (const float*)d_in[0];

    float* ws = (float*)d_ws;
    size_t off = 0;
    auto alloc = [&](size_t n) { float* p = ws + off; off += n; return p; };

    float* hist = alloc((size_t)513 * HB);       // [t][b][k]; slot 0 = h_{-1} = 0
    float* Wt   = alloc((size_t)512 * NP);
    float* WgT  = alloc((size_t)I_ * NP);
    float* WphT = alloc((size_t)H_ * O_);
    float* cb   = alloc(NP);
    float* pb   = alloc(O_);
    int*   bar  = (int*)alloc((size_t)512 * 16); // per-(t,grp) arrival counters
    float* xT3  = alloc((size_t)T_ * I_ * B_);   // [t][i][b]
    // total ~208.5 MB — within the R2-proven workspace (~210.5 MB was OK)

    if (ws_size < off * sizeof(float)) return;

    hipMemsetAsync(hist, 0, HB * sizeof(float), stream);             // h_{-1}=0
    hipMemsetAsync(bar, 0, (size_t)512 * 16 * sizeof(int), stream);  // counters

    PrepArgs pa;
    for (int g = 0; g < 4; ++g) {
        pa.Wxw[g] = (const float*)d_in[1 + 5 * g];
        pa.Wxb[g] = (const float*)d_in[2 + 5 * g];
        pa.Whw[g] = (const float*)d_in[3 + 5 * g];
        pa.Whb[g] = (const float*)d_in[4 + 5 * g];
        pa.bg[g]  = (const float*)d_in[5 + 5 * g];
    }
    pa.Wph_w = (const float*)d_in[21];
    pa.Wph_b = (const float*)d_in[22];
    pa.bp    = (const float*)d_in[23];
    pa.Wt = Wt; pa.WgT = WgT; pa.WphT = WphT;
    pa.cb = cb; pa.pb = pb;

    k_prep<<<(PREP_TOTAL + 255) / 256, 256, 0, stream>>>(pa);
    k_xT3<<<dim3(4, 8, 512), 256, 0, stream>>>(x, xT3);

    k_scanp<<<256, 512, 0, stream>>>(Wt, WgT, xT3, cb, hist, bar);

    k_outproj<<<dim3(2, T_), 256, 0, stream>>>(hist, WphT, pb, (float*)d_out);
    k_softmax<<<T_ * 4, 256, 0, stream>>>((float*)d_out);
}